// Round 7
// baseline (250.782 us; speedup 1.0000x reference)
//
#include <hip/hip_runtime.h>
#include <hip/hip_bf16.h>
#include <string.h>

// Batched GEMM: out[b,o,f] = sum_i W[b,o,i] * x[b,i,f]
// B=32, M(O)=1024, K(I)=1024, N(F)=2048, fp32 in/out, bf16 MFMA compute.
//
// Round-7: same geometry as round 6 (256x256 tile, 512 thr, 8 waves,
// wave tile 128x64, BK=32, LSTR=36, reg-staged cvt_pk -> LDS, double
// buffer, XCD swizzle, lgkm-only barrier). NEW: loop body reordered for
// stage||MFMA overlap:
//   frag ds_reads (half 1 + all B) -> stage(next buf) -> MFMA half 1
//   -> frag ds_reads half 2 -> t+2 global loads -> MFMA half 2 -> barrier
// MFMA half-1 waits only on its ds_reads (counted lgkmcnt); the cvt VALU
// and ds_writes drain under the MFMA clusters. T5 setprio around MFMA.

typedef float  f32x2 __attribute__((ext_vector_type(2)));
typedef float  f32x4 __attribute__((ext_vector_type(4)));
typedef short  bf16x8 __attribute__((ext_vector_type(8)));
typedef unsigned int u32;

#define BATCH 32
#define MDIM 1024
#define KDIM 1024
#define NDIM 2048
#define BM 256
#define BN 256
#define BK 32
#define NT (KDIM / BK)   // 32 K-steps
#define LSTR 36          // ushorts per LDS row: 32 data + 4 pad (18 banks)

__device__ __forceinline__ u32 cvt2(float a, float b) {
    float2 t; t.x = a; t.y = b;
    __hip_bfloat162 h = __float22bfloat162_rn(t);   // v_cvt_pk_bf16_f32 (RTNE)
    u32 r; memcpy(&r, &h, 4);
    return r;
}

// Barrier that does NOT drain vmcnt: LDS visibility only.
__device__ __forceinline__ void lds_barrier() {
    asm volatile("s_waitcnt lgkmcnt(0)" ::: "memory");
    __builtin_amdgcn_s_barrier();
    asm volatile("" ::: "memory");
}

__global__ __launch_bounds__(512, 2) void bgemm_bf16_kernel(
    const float* __restrict__ x, const float* __restrict__ w,
    float* __restrict__ out)
{
    __shared__ unsigned short Ab[2][BM * LSTR];   // W tile  [m][k]  36 KB
    __shared__ unsigned short Bb[2][BN * LSTR];   // x tile^T [n][k] 36 KB

    // ---- XCD-chunked bijective block swizzle (1024 blocks, 1024%8==0) ----
    const int bid  = blockIdx.x;
    const int lbid = (bid & 7) * 128 + (bid >> 3);
    const int bx = lbid & 7;          // n-tile
    const int by = (lbid >> 3) & 3;   // m-tile
    const int bz = lbid >> 5;         // batch

    const int tid = threadIdx.x;
    const int m0  = by * BM;
    const int n0  = bx * BN;

    const int lane = tid & 63;
    const int wid  = tid >> 6;
    const int wm   = (wid >> 2) * 128;   // wave tile 128x64
    const int wn   = (wid & 3)  * 64;
    const int l15  = lane & 15;
    const int kg8  = (lane >> 4) * 8;

    const float* Ag = w + (size_t)bz * MDIM * KDIM + (size_t)m0 * KDIM;
    const float* Bg = x + (size_t)bz * KDIM * NDIM + n0;
    float*       Cg = out + (size_t)bz * MDIM * NDIM + (size_t)m0 * NDIM + n0;

    // ---- A staging map: thread -> rows (tid>>3)+64i, f32x4 col tid&7 ----
    const int a_k4 = tid & 7;
    const int a_m0 = tid >> 3;           // 0..63
    int a_idx[4];
    #pragma unroll
    for (int i = 0; i < 4; ++i)
        a_idx[i] = (a_m0 + 64 * i) * LSTR + 4 * a_k4;
    // ---- B staging map: thread -> k rows 8*(tid>>7)+j, n cols 2*(tid&127) ----
    const int bn0  = 2 * (tid & 127);
    const int b_k0 = 8 * (tid >> 7);     // 0,8,16,24
    int b_idx[2];
    #pragma unroll
    for (int c = 0; c < 2; ++c)
        b_idx[c] = (bn0 + c) * LSTR + b_k0;
    // ---- frag read addrs ----
    int rd_a[8], rd_b[4];
    #pragma unroll
    for (int mi = 0; mi < 8; ++mi)
        rd_a[mi] = (wm + mi * 16 + l15) * LSTR + kg8;
    #pragma unroll
    for (int ni = 0; ni < 4; ++ni)
        rd_b[ni] = (wn + ni * 16 + l15) * LSTR + kg8;

    const float* Ap = Ag + (size_t)a_m0 * KDIM + 4 * a_k4;
    const float* Bp = Bg + (size_t)b_k0 * NDIM + bn0;

    f32x4 acc[8][4];
    #pragma unroll
    for (int i = 0; i < 8; ++i)
        #pragma unroll
        for (int j = 0; j < 4; ++j)
            acc[i][j] = f32x4{0.f, 0.f, 0.f, 0.f};

    f32x4 aav[4];
    f32x2 bbv[8];

    auto load_regs = [&](int kt) {
        #pragma unroll
        for (int i = 0; i < 4; ++i)
            aav[i] = *reinterpret_cast<const f32x4*>(Ap + (size_t)(64 * i) * KDIM + kt);
        #pragma unroll
        for (int j = 0; j < 8; ++j)
            bbv[j] = *reinterpret_cast<const f32x2*>(Bp + (size_t)(kt + j) * NDIM);
    };
    auto stage = [&](int s) {
        #pragma unroll
        for (int i = 0; i < 4; ++i) {
            uint2 v = make_uint2(cvt2(aav[i][0], aav[i][1]),
                                 cvt2(aav[i][2], aav[i][3]));
            *reinterpret_cast<uint2*>(&Ab[s][a_idx[i]]) = v;   // ds_write_b64
        }
        #pragma unroll
        for (int c = 0; c < 2; ++c) {
            uint4 v = make_uint4(cvt2(bbv[0][c], bbv[1][c]),
                                 cvt2(bbv[2][c], bbv[3][c]),
                                 cvt2(bbv[4][c], bbv[5][c]),
                                 cvt2(bbv[6][c], bbv[7][c]));
            *reinterpret_cast<uint4*>(&Bb[s][b_idx[c]]) = v;   // ds_write_b128
        }
    };

    // ---- prologue ----
    load_regs(0);
    stage(0);
    load_regs(BK);
    lds_barrier();

    // ---- main loop ----
    for (int t = 0; t < NT - 1; ++t) {
        const int cur = t & 1;
        bf16x8 bfr[4], af1[4];

        // frag reads: all B + A half-1 (mi 0..3)
        #pragma unroll
        for (int ni = 0; ni < 4; ++ni)
            bfr[ni] = *reinterpret_cast<const bf16x8*>(&Bb[cur][rd_b[ni]]);
        #pragma unroll
        for (int mi = 0; mi < 4; ++mi)
            af1[mi] = *reinterpret_cast<const bf16x8*>(&Ab[cur][rd_a[mi]]);

        // stage tile t+1 into other buffer: cvt VALU + ds_writes drain
        // under the MFMA clusters below (MFMA waits only on its ds_reads).
        stage(cur ^ 1);

        __builtin_amdgcn_s_setprio(1);
        #pragma unroll
        for (int mi = 0; mi < 4; ++mi)
            #pragma unroll
            for (int ni = 0; ni < 4; ++ni)
                acc[mi][ni] = __builtin_amdgcn_mfma_f32_16x16x32_bf16(
                    af1[mi], bfr[ni], acc[mi][ni], 0, 0, 0);
        __builtin_amdgcn_s_setprio(0);

        // A half-2 frag reads + t+2 global loads under half-1 MFMA drain
        bf16x8 af2[4];
        #pragma unroll
        for (int mi = 0; mi < 4; ++mi)
            af2[mi] = *reinterpret_cast<const bf16x8*>(&Ab[cur][rd_a[mi + 4]]);
        int kt2 = (t + 2) * BK;
        if (kt2 > KDIM - BK) kt2 = KDIM - BK;   // clamp (last value unused)
        load_regs(kt2);

        __builtin_amdgcn_s_setprio(1);
        #pragma unroll
        for (int mi = 0; mi < 4; ++mi)
            #pragma unroll
            for (int ni = 0; ni < 4; ++ni)
                acc[mi + 4][ni] = __builtin_amdgcn_mfma_f32_16x16x32_bf16(
                    af2[mi], bfr[ni], acc[mi + 4][ni], 0, 0, 0);
        __builtin_amdgcn_s_setprio(0);

        lds_barrier();
    }

    // ---- tail: tile NT-1, no staging ----
    {
        const int cur = (NT - 1) & 1;
        bf16x8 bfr[4];
        #pragma unroll
        for (int ni = 0; ni < 4; ++ni)
            bfr[ni] = *reinterpret_cast<const bf16x8*>(&Bb[cur][rd_b[ni]]);
        #pragma unroll
        for (int mi = 0; mi < 8; ++mi) {
            bf16x8 af = *reinterpret_cast<const bf16x8*>(&Ab[cur][rd_a[mi]]);
            #pragma unroll
            for (int ni = 0; ni < 4; ++ni)
                acc[mi][ni] = __builtin_amdgcn_mfma_f32_16x16x32_bf16(
                    af, bfr[ni], acc[mi][ni], 0, 0, 0);
        }
    }

    // ---- C store: D layout col=lane&15, row=(lane>>4)*4+reg ----
    const int rbase = (lane >> 4) * 4;
    #pragma unroll
    for (int mi = 0; mi < 8; ++mi) {
        #pragma unroll
        for (int ni = 0; ni < 4; ++ni) {
            int n  = wn + ni * 16 + l15;
            int mb = wm + mi * 16 + rbase;
            #pragma unroll
            for (int r = 0; r < 4; ++r)
                Cg[(size_t)(mb + r) * NDIM + n] = acc[mi][ni][r];
        }
    }
}

extern "C" void kernel_launch(void* const* d_in, const int* in_sizes, int n_in,
                              void* d_out, int out_size, void* d_ws, size_t ws_size,
                              hipStream_t stream) {
    const float* x = (const float*)d_in[0];   // [32][1024][2048]
    const float* w = (const float*)d_in[1];   // [32][1024][1024]
    float* out = (float*)d_out;               // [32][1024][2048]
    const int nblocks = (NDIM / BN) * (MDIM / BM) * BATCH;  // 8*4*32 = 1024
    bgemm_bf16_kernel<<<dim3(nblocks), dim3(512), 0, stream>>>(x, w, out);
}

// Round 8
// 231.889 us; speedup vs baseline: 1.0815x; 1.0815x over previous
//
#include <hip/hip_runtime.h>
#include <hip/hip_bf16.h>
#include <string.h>

// Batched GEMM: out[b,o,f] = sum_i W[b,o,i] * x[b,i,f]
// B=32, M(O)=1024, K(I)=1024, N(F)=2048, fp32 in/out, bf16 MFMA compute.
//
// Round-8: BK 32 -> 64 (halve the per-iteration fixed overhead that r4/r6/r7
// showed is invariant to barrier/ordering changes). 256x256 tile, 512 thr,
// 8 waves (wave tile 128x64). Staging in 2 reg-reusing sub-chunks so VGPR
// stays ~108. LDS rows LSTR=68 ushorts (34 banks, gcd(34,32)=2 -> <=2-way
// on all access classes). LDS 136KB (1 block/CU — already the case).
// lgkm-only barrier, XCD-chunked swizzle, setprio around MFMA clusters.

typedef float  f32x2 __attribute__((ext_vector_type(2)));
typedef float  f32x4 __attribute__((ext_vector_type(4)));
typedef short  bf16x8 __attribute__((ext_vector_type(8)));
typedef unsigned int u32;

#define BATCH 32
#define MDIM 1024
#define KDIM 1024
#define NDIM 2048
#define BM 256
#define BN 256
#define BK 64
#define NT (KDIM / BK)   // 16 K-steps
#define LSTR 68          // ushorts per LDS row: 64 data + 4 pad (34 banks)

__device__ __forceinline__ u32 cvt2(float a, float b) {
    float2 t; t.x = a; t.y = b;
    __hip_bfloat162 h = __float22bfloat162_rn(t);   // v_cvt_pk_bf16_f32 (RTNE)
    u32 r; memcpy(&r, &h, 4);
    return r;
}

// Barrier that does NOT drain vmcnt: LDS visibility only.
__device__ __forceinline__ void lds_barrier() {
    asm volatile("s_waitcnt lgkmcnt(0)" ::: "memory");
    __builtin_amdgcn_s_barrier();
    asm volatile("" ::: "memory");
}

__global__ __launch_bounds__(512, 2) void bgemm_bf16_kernel(
    const float* __restrict__ x, const float* __restrict__ w,
    float* __restrict__ out)
{
    __shared__ unsigned short Ab[2][BM * LSTR];   // W tile  [m][k]  ~34 KB each
    __shared__ unsigned short Bb[2][BN * LSTR];   // x tile^T [n][k] ~34 KB each

    // ---- XCD-chunked bijective block swizzle (1024 blocks, 1024%8==0) ----
    const int bid  = blockIdx.x;
    const int lbid = (bid & 7) * 128 + (bid >> 3);
    const int bx = lbid & 7;          // n-tile
    const int by = (lbid >> 3) & 3;   // m-tile
    const int bz = lbid >> 5;         // batch

    const int tid = threadIdx.x;
    const int m0  = by * BM;
    const int n0  = bx * BN;

    const int lane = tid & 63;
    const int wid  = tid >> 6;
    const int wm   = (wid >> 2) * 128;   // wave tile 128x64
    const int wn   = (wid & 3)  * 64;
    const int l15  = lane & 15;
    const int kg8  = (lane >> 4) * 8;

    const float* Ag = w + (size_t)bz * MDIM * KDIM + (size_t)m0 * KDIM;
    const float* Bg = x + (size_t)bz * KDIM * NDIM + n0;
    float*       Cg = out + (size_t)bz * MDIM * NDIM + (size_t)m0 * NDIM + n0;

    // ---- A staging map: thread -> rows (tid>>4)+32i (i=0..7), f32x4 col tid&15
    const int a_k4 = tid & 15;           // 16 f32x4 cover 64 f32 per row
    const int a_m0 = tid >> 4;           // 0..31
    int a_idx[8];
    #pragma unroll
    for (int i = 0; i < 8; ++i)
        a_idx[i] = (a_m0 + 32 * i) * LSTR + 4 * a_k4;
    // ---- B staging map: chunk h covers k rows 32h + 8*(tid>>7)+j, n cols 2*(tid&127)
    const int bn0  = 2 * (tid & 127);
    const int b_k0 = 8 * (tid >> 7);     // 0,8,16,24
    int b_idx[2];
    #pragma unroll
    for (int c = 0; c < 2; ++c)
        b_idx[c] = (bn0 + c) * LSTR + b_k0;
    // ---- frag read addrs (add 32*kk at use) ----
    int rd_a[8], rd_b[4];
    #pragma unroll
    for (int mi = 0; mi < 8; ++mi)
        rd_a[mi] = (wm + mi * 16 + l15) * LSTR + kg8;
    #pragma unroll
    for (int ni = 0; ni < 4; ++ni)
        rd_b[ni] = (wn + ni * 16 + l15) * LSTR + kg8;

    const float* Ap = Ag + (size_t)a_m0 * KDIM + 4 * a_k4;
    const float* Bp = Bg + (size_t)b_k0 * NDIM + bn0;

    f32x4 acc[8][4];
    #pragma unroll
    for (int i = 0; i < 8; ++i)
        #pragma unroll
        for (int j = 0; j < 4; ++j)
            acc[i][j] = f32x4{0.f, 0.f, 0.f, 0.f};

    f32x4 aav[4];
    f32x2 bbv[8];

    // ---- load sub-chunk h of K-step kt into regs ----
    auto load_regs = [&](int kt, int h) {
        #pragma unroll
        for (int i = 0; i < 4; ++i)
            aav[i] = *reinterpret_cast<const f32x4*>(
                Ap + (size_t)(32 * (i + 4 * h)) * KDIM + kt);
        #pragma unroll
        for (int j = 0; j < 8; ++j)
            bbv[j] = *reinterpret_cast<const f32x2*>(
                Bp + (size_t)(kt + 32 * h + j) * NDIM);
    };
    // ---- cvt + LDS write of reg sub-chunk h into buffer s ----
    auto stage = [&](int s, int h) {
        #pragma unroll
        for (int i = 0; i < 4; ++i) {
            uint2 v = make_uint2(cvt2(aav[i][0], aav[i][1]),
                                 cvt2(aav[i][2], aav[i][3]));
            *reinterpret_cast<uint2*>(&Ab[s][a_idx[i + 4 * h]]) = v; // b64
        }
        #pragma unroll
        for (int c = 0; c < 2; ++c) {
            uint4 v = make_uint4(cvt2(bbv[0][c], bbv[1][c]),
                                 cvt2(bbv[2][c], bbv[3][c]),
                                 cvt2(bbv[4][c], bbv[5][c]),
                                 cvt2(bbv[6][c], bbv[7][c]));
            *reinterpret_cast<uint4*>(&Bb[s][b_idx[c] + 32 * h]) = v; // b128
        }
    };

    // ---- prologue: stage tile 0 fully, load (tile1, chunk0) ----
    load_regs(0, 0);
    stage(0, 0);
    load_regs(0, 1);
    stage(0, 1);
    load_regs(BK, 0);
    lds_barrier();

    // ---- main loop: compute tile t, stage tile t+1 ----
    for (int t = 0; t < NT - 1; ++t) {
        const int cur = t & 1;
        const int ktn = (t + 1) * BK;
        bf16x8 bfr[4], af[4];

        // ===== kk = 0 =====
        #pragma unroll
        for (int ni = 0; ni < 4; ++ni)
            bfr[ni] = *reinterpret_cast<const bf16x8*>(&Bb[cur][rd_b[ni]]);
        #pragma unroll
        for (int mi = 0; mi < 4; ++mi)
            af[mi] = *reinterpret_cast<const bf16x8*>(&Ab[cur][rd_a[mi]]);

        stage(cur ^ 1, 0);          // chunk0 of tile t+1 (regs from last iter)
        load_regs(ktn, 1);          // chunk1 -> regs

        __builtin_amdgcn_s_setprio(1);
        #pragma unroll
        for (int mi = 0; mi < 4; ++mi)
            #pragma unroll
            for (int ni = 0; ni < 4; ++ni)
                acc[mi][ni] = __builtin_amdgcn_mfma_f32_16x16x32_bf16(
                    af[mi], bfr[ni], acc[mi][ni], 0, 0, 0);
        __builtin_amdgcn_s_setprio(0);

        #pragma unroll
        for (int mi = 0; mi < 4; ++mi)
            af[mi] = *reinterpret_cast<const bf16x8*>(&Ab[cur][rd_a[mi + 4]]);

        __builtin_amdgcn_s_setprio(1);
        #pragma unroll
        for (int mi = 0; mi < 4; ++mi)
            #pragma unroll
            for (int ni = 0; ni < 4; ++ni)
                acc[mi + 4][ni] = __builtin_amdgcn_mfma_f32_16x16x32_bf16(
                    af[mi], bfr[ni], acc[mi + 4][ni], 0, 0, 0);
        __builtin_amdgcn_s_setprio(0);

        // ===== kk = 1 =====
        #pragma unroll
        for (int ni = 0; ni < 4; ++ni)
            bfr[ni] = *reinterpret_cast<const bf16x8*>(&Bb[cur][rd_b[ni] + 32]);
        #pragma unroll
        for (int mi = 0; mi < 4; ++mi)
            af[mi] = *reinterpret_cast<const bf16x8*>(&Ab[cur][rd_a[mi] + 32]);

        stage(cur ^ 1, 1);          // chunk1 of tile t+1
        int kt2 = (t + 2) * BK;
        if (kt2 > KDIM - BK) kt2 = KDIM - BK;   // clamp (last value unused)
        load_regs(kt2, 0);          // next iter's chunk0

        __builtin_amdgcn_s_setprio(1);
        #pragma unroll
        for (int mi = 0; mi < 4; ++mi)
            #pragma unroll
            for (int ni = 0; ni < 4; ++ni)
                acc[mi][ni] = __builtin_amdgcn_mfma_f32_16x16x32_bf16(
                    af[mi], bfr[ni], acc[mi][ni], 0, 0, 0);
        __builtin_amdgcn_s_setprio(0);

        #pragma unroll
        for (int mi = 0; mi < 4; ++mi)
            af[mi] = *reinterpret_cast<const bf16x8*>(&Ab[cur][rd_a[mi + 4] + 32]);

        __builtin_amdgcn_s_setprio(1);
        #pragma unroll
        for (int mi = 0; mi < 4; ++mi)
            #pragma unroll
            for (int ni = 0; ni < 4; ++ni)
                acc[mi + 4][ni] = __builtin_amdgcn_mfma_f32_16x16x32_bf16(
                    af[mi], bfr[ni], acc[mi + 4][ni], 0, 0, 0);
        __builtin_amdgcn_s_setprio(0);

        lds_barrier();
    }

    // ---- tail: tile NT-1, both kk, no staging ----
    {
        const int cur = (NT - 1) & 1;
        #pragma unroll
        for (int kk = 0; kk < 2; ++kk) {
            bf16x8 bfr[4];
            #pragma unroll
            for (int ni = 0; ni < 4; ++ni)
                bfr[ni] = *reinterpret_cast<const bf16x8*>(
                    &Bb[cur][rd_b[ni] + 32 * kk]);
            #pragma unroll
            for (int mi = 0; mi < 8; ++mi) {
                bf16x8 af = *reinterpret_cast<const bf16x8*>(
                    &Ab[cur][rd_a[mi] + 32 * kk]);
                #pragma unroll
                for (int ni = 0; ni < 4; ++ni)
                    acc[mi][ni] = __builtin_amdgcn_mfma_f32_16x16x32_bf16(
                        af, bfr[ni], acc[mi][ni], 0, 0, 0);
            }
        }
    }

    // ---- C store: D layout col=lane&15, row=(lane>>4)*4+reg ----
    const int rbase = (lane >> 4) * 4;
    #pragma unroll
    for (int mi = 0; mi < 8; ++mi) {
        #pragma unroll
        for (int ni = 0; ni < 4; ++ni) {
            int n  = wn + ni * 16 + l15;
            int mb = wm + mi * 16 + rbase;
            #pragma unroll
            for (int r = 0; r < 4; ++r)
                Cg[(size_t)(mb + r) * NDIM + n] = acc[mi][ni][r];
        }
    }
}

extern "C" void kernel_launch(void* const* d_in, const int* in_sizes, int n_in,
                              void* d_out, int out_size, void* d_ws, size_t ws_size,
                              hipStream_t stream) {
    const float* x = (const float*)d_in[0];   // [32][1024][2048]
    const float* w = (const float*)d_in[1];   // [32][1024][1024]
    float* out = (float*)d_out;               // [32][1024][2048]
    const int nblocks = (NDIM / BN) * (MDIM / BM) * BATCH;  // 8*4*32 = 1024
    bgemm_bf16_kernel<<<dim3(nblocks), dim3(512), 0, stream>>>(x, w, out);
}